// Round 3
// baseline (23485.378 us; speedup 1.0000x reference)
//
#include <hip/hip_runtime.h>
#include <stdint.h>

typedef unsigned short u16;
typedef unsigned int   u32;
typedef __bf16 bf16_t;
typedef bf16_t bf16x8 __attribute__((ext_vector_type(8)));
typedef float  f32x4  __attribute__((ext_vector_type(4)));

#define NSTEPS 512

// ---- R12: batch-row partition, zero inter-block sync. ----
// 16 blocks x 1024 threads. Block bt owns batch rows bt*16..+15 for BOTH
// layers; h1/h2 state lives in block LDS; weights stream from L2 each step.
// ws holds pre-swizzled bf16 weight subtiles (one-time conversion kernel):
// subtile = 1KB = 16 N-rows x 32 K-cols in MFMA-B-fragment order:
//   lane l holds row (l&15), cols (l>>4)*8..+7  ->  u16 index = l*8+e
// Region layout: [w 0..15][g 0..3][kc] subtiles, so wave w's per-step
// stream is a contiguous block.
#define WS_W0X 0u         /* Wih0: 16w x 4g x 2kc x 1KB = 128KB */
#define WS_W0H 131072u    /* Whh0: 16w x 4g x 8kc x 1KB = 512KB */
#define WS_W1X 655360u    /* Wih1: 512KB */
#define WS_W1H 1179648u   /* Whh1: 512KB */
#define WS_TOTAL 1703936u

// LDS (u16 units): h tiles padded to stride 264 (breaks 512B bank cycle).
#define H1OFF 0           /* [16][264] u16 = 8448 */
#define H2OFF 4224
#define EPI_OFF 8448      /* byte 16896: epilogue f32 scratch */
#define SMEM_BYTES 116736 /* 16896 + 16KB lastsh + 80KB y1 + 1KB psum */

__device__ __forceinline__ u16 f2bf(float f) {
  u32 u = __float_as_uint(f);
  return (u16)((u + 0x7fffu + ((u >> 16) & 1u)) >> 16);   // RNE
}
__device__ __forceinline__ float bf2f(u16 b) { return __uint_as_float(((u32)b) << 16); }
__device__ __forceinline__ float sigf(float x) { return 1.f / (1.f + __expf(-x)); }
__device__ __forceinline__ float tanhf_(float x) {
  float e = __expf(-2.f * fabsf(x));
  float t = (1.f - e) / (1.f + e);
  return x >= 0.f ? t : -t;
}
__device__ __forceinline__ bf16x8 pack_bf8(float4 a, float4 b) {
  union { u32 w[4]; bf16x8 v; } u_;
  u_.w[0] = (u32)f2bf(a.x) | ((u32)f2bf(a.y) << 16);
  u_.w[1] = (u32)f2bf(a.z) | ((u32)f2bf(a.w) << 16);
  u_.w[2] = (u32)f2bf(b.x) | ((u32)f2bf(b.y) << 16);
  u_.w[3] = (u32)f2bf(b.z) | ((u32)f2bf(b.w) << 16);
  return u_.v;
}

// one-time: fp32 weights -> bf16 subtiles in ws (stream order).
// u16 output index -> (region, subtile s, lane, elem) -> source (row, col).
__global__ void conv_weights(const float* __restrict__ Wih0,
                             const float* __restrict__ Whh0,
                             const float* __restrict__ Wih1,
                             const float* __restrict__ Whh1,
                             u16* __restrict__ wsw)
{
  int idx = blockIdx.x * blockDim.x + threadIdx.x;
  const float* src; int base, NKC, K;
  if      (idx < 65536)  { src = Wih0; base = 0;      NKC = 2; K = 64;  }
  else if (idx < 327680) { src = Whh0; base = 65536;  NKC = 8; K = 256; }
  else if (idx < 589824) { src = Wih1; base = 327680; NKC = 8; K = 256; }
  else if (idx < 851968) { src = Whh1; base = 589824; NKC = 8; K = 256; }
  else return;
  int r = idx - base;
  int s = r >> 9, within = r & 511;
  int lane = within >> 3, e = within & 7;
  int kc = s % NKC, t2 = s / NKC;          // t2 = w*4 + g
  int g = t2 & 3, w = t2 >> 2;
  int row = g*256 + w*16 + (lane & 15);
  int col = kc*32 + (lane >> 4)*8 + e;
  wsw[idx] = f2bf(src[(size_t)row*K + col]);
}

// Persistent-free batch-parallel 2-layer LSTM. Wave wv owns h-cols
// 16*wv..+15 (all 4 gates -> pointwise is lane-local: C col=lane&15,
// rows quad*4+r). A-fragments (h state) come from LDS h tiles; next-step
// redistribution is 4 ds_write_b16 + barrier (replaces R9's LLC ring).
__global__ void __launch_bounds__(1024)
lstm_batchpar(const float* __restrict__ x,
              const float* __restrict__ bih0, const float* __restrict__ bhh0,
              const float* __restrict__ bih1, const float* __restrict__ bhh1,
              const float* __restrict__ W1, const float* __restrict__ b1,
              const float* __restrict__ W2, const float* __restrict__ b2,
              float* __restrict__ out, const char* __restrict__ ws)
{
  extern __shared__ u16 smem[];
  const int tid  = threadIdx.x;
  const int lane = tid & 63;
  const int wv   = tid >> 6;           // 0..15
  const int n16  = lane & 15;
  const int quad = lane >> 4;
  const int bt   = blockIdx.x;         // batch rows bt*16..+15
  const int lofs = lane * 8;           // u16 offset of lane's B-frag in subtile

  const u16* w0x = (const u16*)(ws + WS_W0X) + wv*(4*2*512);
  const u16* w0h = (const u16*)(ws + WS_W0H) + wv*(4*8*512);
  const u16* w1x = (const u16*)(ws + WS_W1X) + wv*(4*8*512);
  const u16* w1h = (const u16*)(ws + WS_W1H) + wv*(4*8*512);

  float bg0[4], bg1[4];
  #pragma unroll
  for (int g = 0; g < 4; ++g) {
    int wrow = g*256 + wv*16 + n16;
    bg0[g] = bih0[wrow] + bhh0[wrow];
    bg1[g] = bih1[wrow] + bhh1[wrow];
  }
  f32x4 c1 = {0.f,0.f,0.f,0.f}, c2 = {0.f,0.f,0.f,0.f};

  u16* h1t = smem + H1OFF;
  u16* h2t = smem + H2OFF;
  for (int i = tid; i < 8448; i += 1024) smem[i] = 0;   // h_{-1} = 0
  __syncthreads();

  const float* xrow = x + (size_t)(bt*16 + n16) * NSTEPS * 64;

  for (int t = 0; t < NSTEPS; ++t) {
    // ---- 1: A-frags for h1_{t-1}, h2_{t-1} (reads before overwrite) ----
    bf16x8 a1[8], a2[8];
    #pragma unroll
    for (int kc = 0; kc < 8; ++kc) {
      a1[kc] = *(const bf16x8*)(h1t + n16*264 + kc*32 + quad*8);
      a2[kc] = *(const bf16x8*)(h2t + n16*264 + kc*32 + quad*8);
    }
    const float* xp = xrow + (size_t)t*64 + quad*8;
    float4 xa = *(const float4*)(xp);
    float4 xb = *(const float4*)(xp + 4);
    float4 xc = *(const float4*)(xp + 32);
    float4 xd = *(const float4*)(xp + 36);
    bf16x8 ax0 = pack_bf8(xa, xb), ax1 = pack_bf8(xc, xd);
    __syncthreads();                       // all reads of old tiles done

    // ---- 3: layer 0 (x part + h1 recurrence), weights streamed ----
    f32x4 acc[4];
    #pragma unroll
    for (int g = 0; g < 4; ++g) acc[g] = (f32x4){0.f,0.f,0.f,0.f};
    #pragma unroll
    for (int g = 0; g < 4; ++g) {
      acc[g] = __builtin_amdgcn_mfma_f32_16x16x32_bf16(
          ax0, *(const bf16x8*)(w0x + (g*2+0)*512 + lofs), acc[g], 0,0,0);
      acc[g] = __builtin_amdgcn_mfma_f32_16x16x32_bf16(
          ax1, *(const bf16x8*)(w0x + (g*2+1)*512 + lofs), acc[g], 0,0,0);
    }
    #pragma unroll
    for (int kc = 0; kc < 8; ++kc)
      #pragma unroll
      for (int g = 0; g < 4; ++g)
        acc[g] = __builtin_amdgcn_mfma_f32_16x16x32_bf16(
            a1[kc], *(const bf16x8*)(w0h + (g*8+kc)*512 + lofs), acc[g], 0,0,0);
    #pragma unroll
    for (int r = 0; r < 4; ++r) {          // rows quad*4+r, col wv*16+n16
      float gi = acc[0][r] + bg0[0];
      float gf = acc[1][r] + bg0[1];
      float gg = acc[2][r] + bg0[2];
      float go = acc[3][r] + bg0[3];
      float c  = sigf(gf)*c1[r] + sigf(gi)*tanhf_(gg);
      c1[r] = c;
      h1t[(quad*4+r)*264 + wv*16 + n16] = f2bf(sigf(go)*tanhf_(c));
    }
    __syncthreads();                       // h1_t visible

    // ---- 5/6: layer 1 (h1_t + h2 recurrence) ----
    bf16x8 a1n[8];
    #pragma unroll
    for (int kc = 0; kc < 8; ++kc)
      a1n[kc] = *(const bf16x8*)(h1t + n16*264 + kc*32 + quad*8);
    f32x4 acc2[4];
    #pragma unroll
    for (int g = 0; g < 4; ++g) acc2[g] = (f32x4){0.f,0.f,0.f,0.f};
    #pragma unroll
    for (int kc = 0; kc < 8; ++kc)
      #pragma unroll
      for (int g = 0; g < 4; ++g)
        acc2[g] = __builtin_amdgcn_mfma_f32_16x16x32_bf16(
            a1n[kc], *(const bf16x8*)(w1x + (g*8+kc)*512 + lofs), acc2[g], 0,0,0);
    #pragma unroll
    for (int kc = 0; kc < 8; ++kc)
      #pragma unroll
      for (int g = 0; g < 4; ++g)
        acc2[g] = __builtin_amdgcn_mfma_f32_16x16x32_bf16(
            a2[kc], *(const bf16x8*)(w1h + (g*8+kc)*512 + lofs), acc2[g], 0,0,0);
    #pragma unroll
    for (int r = 0; r < 4; ++r) {
      float gi = acc2[0][r] + bg1[0];
      float gf = acc2[1][r] + bg1[1];
      float gg = acc2[2][r] + bg1[2];
      float go = acc2[3][r] + bg1[3];
      float c  = sigf(gf)*c2[r] + sigf(gi)*tanhf_(gg);
      c2[r] = c;
      h2t[(quad*4+r)*264 + wv*16 + n16] = f2bf(sigf(go)*tanhf_(c));
    }
    __syncthreads();                       // h2_t visible for next iter
  }

  // ======== epilogue: y = (h2_T @ W1^T + b1) @ W2^T + b2 (block-local) ====
  {
    float* lastsh = (float*)(smem + EPI_OFF);   // 16 x 256
    float* y1sh   = lastsh + 4096;              // 16 x 1280
    float* psum   = y1sh + 20480;               // 256
    {
      int row = tid >> 6, c = tid & 63;
      #pragma unroll
      for (int i = 0; i < 4; ++i) {
        int col = c + i*64;
        lastsh[row*256 + col] = bf2f(h2t[row*264 + col]);
      }
    }
    __syncthreads();
    for (int i = 0; i < 2; ++i) {
      int m = tid + i*1024;
      if (m < 1280) {
        const float* wr = W1 + (size_t)m*256;
        float a[16];
        #pragma unroll
        for (int j = 0; j < 16; ++j) a[j] = 0.f;
        for (int k = 0; k < 256; ++k) {
          float w = wr[k];
          #pragma unroll
          for (int j = 0; j < 16; ++j) a[j] += w * lastsh[j*256 + k];
        }
        float bb = b1[m];
        #pragma unroll
        for (int j = 0; j < 16; ++j) y1sh[j*1280 + m] = a[j] + bb;
      }
    }
    __syncthreads();
    if (tid < 256) {
      int row = tid >> 4, o = (tid >> 2) & 3, q = tid & 3;
      const float* w2r = W2 + (size_t)o*1280 + q*320;
      const float* yr  = y1sh + row*1280 + q*320;
      float s = 0.f;
      for (int m = 0; m < 320; ++m) s += w2r[m]*yr[m];
      psum[tid] = s;
    }
    __syncthreads();
    if (tid < 64) {
      int row = tid >> 2, o = tid & 3;
      out[(bt*16 + row)*4 + o] = b2[o] + psum[row*16 + o*4 + 0]
                                       + psum[row*16 + o*4 + 1]
                                       + psum[row*16 + o*4 + 2]
                                       + psum[row*16 + o*4 + 3];
    }
  }
}

extern "C" void kernel_launch(void* const* d_in, const int* in_sizes, int n_in,
                              void* d_out, int out_size, void* d_ws, size_t ws_size,
                              hipStream_t stream) {
  (void)in_sizes; (void)n_in; (void)out_size; (void)ws_size;
  const float* x    = (const float*)d_in[0];
  const float* Wih0 = (const float*)d_in[1];
  const float* Whh0 = (const float*)d_in[2];
  const float* bih0 = (const float*)d_in[3];
  const float* bhh0 = (const float*)d_in[4];
  const float* Wih1 = (const float*)d_in[5];
  const float* Whh1 = (const float*)d_in[6];
  const float* bih1 = (const float*)d_in[7];
  const float* bhh1 = (const float*)d_in[8];
  const float* W1   = (const float*)d_in[9];
  const float* b1   = (const float*)d_in[10];
  const float* W2   = (const float*)d_in[11];
  const float* b2   = (const float*)d_in[12];
  float* out = (float*)d_out;
  char* ws   = (char*)d_ws;

  // one-time-per-call: fp32 -> bf16 subtile swizzle into ws (851968 u16)
  hipLaunchKernelGGL(conv_weights, dim3(3328), dim3(256), 0, stream,
                     Wih0, Whh0, Wih1, Whh1, (u16*)ws);

  hipFuncSetAttribute((const void*)lstm_batchpar,
                      hipFuncAttributeMaxDynamicSharedMemorySize, SMEM_BYTES);

  hipLaunchKernelGGL(lstm_batchpar, dim3(16), dim3(1024), SMEM_BYTES, stream,
                     x, bih0, bhh0, bih1, bhh1, W1, b1, W2, b2, out, ws);
}

// Round 4
// 9226.380 us; speedup vs baseline: 2.5455x; 2.5455x over previous
//
#include <hip/hip_runtime.h>
#include <stdint.h>

typedef unsigned short u16;
typedef unsigned int   u32;
typedef unsigned long long u64;
typedef __bf16 bf16_t;
typedef bf16_t bf16x8 __attribute__((ext_vector_type(8)));
typedef float  f32x4  __attribute__((ext_vector_type(4)));
typedef int    i32x4  __attribute__((ext_vector_type(4)));

#define NSTEPS 512
#define SPIN_LIM  (1<<17)
#define RETRY_LIM (1<<13)

// ---- workspace (bytes). Rings store u32 words: (step_tag<<16)|h_bf16 ->
// data is self-validating. Publish = relaxed agent-scope atomic swap
// (executes at LLC). R13: 4-chain round-robin interleave — 32 blocks
// (16 col-slices x 2 layers); each block cycles batch groups 0..3 per
// step so LLC publish->poll latency of chain bi hides under compute of
// the other three chains. Per-(chain,step) mechanics verbatim R9.
#define WS_RING1 0u          /* [4 grp][4 slot][64 row][256 col] u32 h1 */
#define WS_RING2 1048576u    /* [4 grp][4 slot][64 row][256 col] u32 h2 */
#define WS_PROG  2097152u    /* [4 grp][64] int: L1 per-wave read progress */
#define WS_TOTAL 2098176u

#define SMEM_BYTES 99328   /* epilogue 16KB+80KB+1KB; L1 weights 66560; L0 41984 */

__device__ __forceinline__ u16 f2bf(float f) {
  u32 u = __float_as_uint(f);
  return (u16)((u + 0x7fffu + ((u >> 16) & 1u)) >> 16);   // RNE
}
__device__ __forceinline__ float bf2f(u16 b) { return __uint_as_float(((u32)b) << 16); }
__device__ __forceinline__ float sigf(float x) { return 1.f / (1.f + __expf(-x)); }
__device__ __forceinline__ float tanhf_(float x) {
  float e = __expf(-2.f * fabsf(x));
  float t = (1.f - e) / (1.f + e);
  return x >= 0.f ? t : -t;
}

// publish: atomic swap at agent scope -> RMW executed at the LLC,
// data visible at fabric latency, line resident for consumer polls.
__device__ __forceinline__ void pub_u32(u32* p, u32 v) {
  (void)__hip_atomic_exchange(p, v, __ATOMIC_RELAXED, __HIP_MEMORY_SCOPE_AGENT);
}
__device__ __forceinline__ u64 ld_u64_sc1(const u64* p) {
  u64 v; asm volatile("global_load_dwordx2 %0, %1, off sc1\n\ts_waitcnt vmcnt(0)"
                      : "=v"(v) : "v"(p) : "memory"); return v;
}

// 16 x 16B loads of a lane's 64 tagged words (8 chunks of 32 cols; lane
// covers cols quad*8..+7 of each chunk; row stride 1024B) + vmcnt(0).
#define LD16_W(A, P)                                                       \
  asm volatile(                                                            \
    "global_load_dwordx4 %0,  %16, off sc1\n\t"                            \
    "global_load_dwordx4 %1,  %16, off offset:16 sc1\n\t"                  \
    "global_load_dwordx4 %2,  %16, off offset:128 sc1\n\t"                 \
    "global_load_dwordx4 %3,  %16, off offset:144 sc1\n\t"                 \
    "global_load_dwordx4 %4,  %16, off offset:256 sc1\n\t"                 \
    "global_load_dwordx4 %5,  %16, off offset:272 sc1\n\t"                 \
    "global_load_dwordx4 %6,  %16, off offset:384 sc1\n\t"                 \
    "global_load_dwordx4 %7,  %16, off offset:400 sc1\n\t"                 \
    "global_load_dwordx4 %8,  %16, off offset:512 sc1\n\t"                 \
    "global_load_dwordx4 %9,  %16, off offset:528 sc1\n\t"                 \
    "global_load_dwordx4 %10, %16, off offset:640 sc1\n\t"                 \
    "global_load_dwordx4 %11, %16, off offset:656 sc1\n\t"                 \
    "global_load_dwordx4 %12, %16, off offset:768 sc1\n\t"                 \
    "global_load_dwordx4 %13, %16, off offset:784 sc1\n\t"                 \
    "global_load_dwordx4 %14, %16, off offset:896 sc1\n\t"                 \
    "global_load_dwordx4 %15, %16, off offset:912 sc1\n\t"                 \
    "s_waitcnt vmcnt(0)"                                                   \
    : "=&v"(A[0]), "=&v"(A[1]), "=&v"(A[2]),  "=&v"(A[3]),                 \
      "=&v"(A[4]), "=&v"(A[5]), "=&v"(A[6]),  "=&v"(A[7]),                 \
      "=&v"(A[8]), "=&v"(A[9]), "=&v"(A[10]), "=&v"(A[11]),                \
      "=&v"(A[12]),"=&v"(A[13]),"=&v"(A[14]), "=&v"(A[15])                 \
    : "v"(P) : "memory")

#define TAGCHK(A, TB, BAD) do {                                            \
    _Pragma("unroll")                                                      \
    for (int q_ = 0; q_ < 16; ++q_)                                        \
      BAD |= ((u32)A[q_][0] ^ TB) | ((u32)A[q_][1] ^ TB)                   \
           | ((u32)A[q_][2] ^ TB) | ((u32)A[q_][3] ^ TB);                  \
  } while (0)

// poll the data itself until every word's tag == want (self-validating sync)
#define TAGPOLL(A, hp, want) do {                                          \
    u32 tb = ((u32)(want)) << 16; int it_ = 0;                             \
    for (;;) {                                                             \
      LD16_W(A, hp);                                                       \
      u32 bad = 0; TAGCHK(A, tb, bad); bad &= 0xffff0000u;                 \
      if (__all(bad == 0)) break;                                          \
      if (++it_ > RETRY_LIM) break;                                        \
      __builtin_amdgcn_s_sleep(1);                                         \
    }                                                                      \
  } while (0)

__device__ __forceinline__ bf16x8 frag_from(i32x4 lo, i32x4 hi) {
  union { u32 w[4]; bf16x8 v; } u_;
  u_.w[0] = ((u32)lo[0] & 0xffffu) | ((u32)lo[1] << 16);
  u_.w[1] = ((u32)lo[2] & 0xffffu) | ((u32)lo[3] << 16);
  u_.w[2] = ((u32)hi[0] & 0xffffu) | ((u32)hi[1] << 16);
  u_.w[3] = ((u32)hi[2] & 0xffffu) | ((u32)hi[3] << 16);
  return u_.v;
}
__device__ __forceinline__ bf16x8 pack_bf8(float4 a, float4 b) {
  union { u32 w[4]; bf16x8 v; } u_;
  u_.w[0] = (u32)f2bf(a.x) | ((u32)f2bf(a.y) << 16);
  u_.w[1] = (u32)f2bf(a.z) | ((u32)f2bf(a.w) << 16);
  u_.w[2] = (u32)f2bf(b.x) | ((u32)f2bf(b.y) << 16);
  u_.w[3] = (u32)f2bf(b.z) | ((u32)f2bf(b.w) << 16);
  return u_.v;
}

// anti-dep spin (L0, every 2nd step): lanes watch L1 read-progress words
__device__ __forceinline__ void spin64(const int* f, int lane, int target) {
  if (target <= 0) return;
  int it = 0;
  for (;;) {
    int v = __hip_atomic_load(&f[lane], __ATOMIC_RELAXED, __HIP_MEMORY_SCOPE_AGENT);
    if (__all(v >= target)) return;
    if (++it > SPIN_LIM) return;
    __builtin_amdgcn_s_sleep(2);
  }
}

__global__ void ws_init_kernel(int* p, int n) {
  int i = blockIdx.x * blockDim.x + threadIdx.x;
  if (i < n)    // agent-scope stores -> zeros at LLC (tag0 == h_{-1}=0)
    __hip_atomic_store(&p[i], 0, __ATOMIC_RELAXED, __HIP_MEMORY_SCOPE_AGENT);
}

// Pipelined persistent 2-layer LSTM, 32 blocks x 256 threads.
// blk<16: layer-0 worker; blk>=16: layer-1 worker (+ epilogue).
// j=blk&15: 16-col slice. Each block round-robins the 4 independent
// batch-group chains (bi=0..3) per step t: publish latency of chain bi
// hides under compute of bi+1..bi+3. Wave wv = M-tile (16 rows).
// MFMA 16x16x32_bf16: A from tagged LLC ring (registers), B from
// row-major padded LDS, C/D col=lane&15, row=quad*4+reg -> acc[nt]=gate,
// lane-local pointwise, c-state in VGPRs (cst[bi][r], bi-loop unrolled).
__global__ void __launch_bounds__(256)
lstm_persistent(const float* __restrict__ x,
                const float* __restrict__ Wih0, const float* __restrict__ Whh0,
                const float* __restrict__ bih0, const float* __restrict__ bhh0,
                const float* __restrict__ Wih1, const float* __restrict__ Whh1,
                const float* __restrict__ bih1, const float* __restrict__ bhh1,
                const float* __restrict__ W1, const float* __restrict__ b1,
                const float* __restrict__ W2, const float* __restrict__ b2,
                float* __restrict__ out, char* __restrict__ ws)
{
  extern __shared__ u16 smem[];
  const int tid  = threadIdx.x;
  const int lane = tid & 63;
  const int wv   = tid >> 6;
  const int n16  = lane & 15;
  const int quad = lane >> 4;
  const int blk  = blockIdx.x;
  const int layer = blk >> 4;
  const int j    = blk & 15;
  const int j16  = j * 16;
  const int widx = j*4 + wv;
  const int arow = wv*16 + n16;          // my A-row (group-local)

  u32* ring1 = (u32*)(ws + WS_RING1);
  u32* ring2 = (u32*)(ws + WS_RING2);
  int* prog  = (int*)(ws + WS_PROG);

  float bg[4];
  #pragma unroll
  for (int nt = 0; nt < 4; ++nt) {
    int wrow = nt*256 + j16 + n16;
    bg[nt] = layer ? (bih1[wrow] + bhh1[wrow]) : (bih0[wrow] + bhh0[wrow]);
  }
  float cst[4][4];                       // [chain][r], static-indexed (unrolled)
  #pragma unroll
  for (int bi = 0; bi < 4; ++bi)
    #pragma unroll
    for (int r = 0; r < 4; ++r) cst[bi][r] = 0.f;
  i32x4 h[16];

  if (layer == 0) {
    // ---- stage W0 slice fp32->bf16 into LDS, row-major stride 328 ----
    for (int i = 0; i < 20; ++i) {
      int u = tid + i*256;               // 64 rows x 80 float4
      int lr = u / 80, c4 = u % 80;
      int wrow = (lr >> 4)*256 + j16 + (lr & 15);
      float4 v = (c4 < 16) ? *(const float4*)(Wih0 + (size_t)wrow*64 + c4*4)
                           : *(const float4*)(Whh0 + (size_t)wrow*256 + (c4-16)*4);
      u16* d = smem + lr*328 + c4*4;
      d[0]=f2bf(v.x); d[1]=f2bf(v.y); d[2]=f2bf(v.z); d[3]=f2bf(v.w);
    }
    __syncthreads();
    const u16* bP = smem + n16*328 + quad*8;

    for (int t = 0; t < NSTEPS; ++t) {
      #pragma unroll
      for (int bi = 0; bi < 4; ++bi) {
        u32* r1g = ring1 + (size_t)bi * 65536;
        int* prg = prog + bi * 64;
        // x_t prefetch (in flight during spin/poll)
        const float* xp = x + ((size_t)(bi*64 + arow)*NSTEPS + t)*64 + quad*8;
        float4 xa = *(const float4*)(xp);
        float4 xb = *(const float4*)(xp + 4);
        float4 xc = *(const float4*)(xp + 32);
        float4 xd = *(const float4*)(xp + 36);
        if ((t & 1) == 0)
          spin64(prg, lane, t - 2);   // ring1 anti-dep, amortized over 2 steps
        { const char* hp = (const char*)(r1g + ((t+3)&3)*16384) + arow*1024 + quad*32;
          TAGPOLL(h, hp, t); }        // h1_{t-1}: tag t (t=0 -> zeros)
        bf16x8 a0 = pack_bf8(xa, xb), a1 = pack_bf8(xc, xd);
        f32x4 acc[4] = {{0,0,0,0},{0,0,0,0},{0,0,0,0},{0,0,0,0}};
        #pragma unroll
        for (int nt = 0; nt < 4; ++nt)
          acc[nt] = __builtin_amdgcn_mfma_f32_16x16x32_bf16(
              a0, *(const bf16x8*)(bP + nt*16*328), acc[nt], 0,0,0);
        #pragma unroll
        for (int nt = 0; nt < 4; ++nt)
          acc[nt] = __builtin_amdgcn_mfma_f32_16x16x32_bf16(
              a1, *(const bf16x8*)(bP + nt*16*328 + 32), acc[nt], 0,0,0);
        #pragma unroll
        for (int kc = 0; kc < 8; ++kc) {
          bf16x8 a = frag_from(h[2*kc], h[2*kc+1]);
          #pragma unroll
          for (int nt = 0; nt < 4; ++nt)
            acc[nt] = __builtin_amdgcn_mfma_f32_16x16x32_bf16(
                a, *(const bf16x8*)(bP + nt*16*328 + 64 + kc*32), acc[nt], 0,0,0);
        }
        u32 tag = ((u32)(t+1)) << 16;
        u32* dst = r1g + (t&3)*16384;
        #pragma unroll
        for (int r = 0; r < 4; ++r) {
          float gi = acc[0][r] + bg[0];
          float gf = acc[1][r] + bg[1];
          float gg = acc[2][r] + bg[2];
          float go = acc[3][r] + bg[3];
          float c  = sigf(gf)*cst[bi][r] + sigf(gi)*tanhf_(gg);
          cst[bi][r] = c;
          int rl = wv*16 + quad*4 + r;
          pub_u32(dst + rl*256 + j16 + n16, tag | (u32)f2bf(sigf(go)*tanhf_(c)));
        }
      }
    }
    return;
  }

  // ======================= LAYER-1 WORKER =======================
  for (int i = 0; i < 32; ++i) {
    int u = tid + i*256;               // 64 rows x 128 float4 ([Wih1|Whh1])
    int lr = u >> 7, c4 = u & 127;
    int wrow = (lr >> 4)*256 + j16 + (lr & 15);
    float4 v = (c4 < 64) ? *(const float4*)(Wih1 + (size_t)wrow*256 + c4*4)
                         : *(const float4*)(Whh1 + (size_t)wrow*256 + (c4-64)*4);
    u16* d = smem + lr*520 + c4*4;
    d[0]=f2bf(v.x); d[1]=f2bf(v.y); d[2]=f2bf(v.z); d[3]=f2bf(v.w);
  }
  __syncthreads();
  const u16* bP = smem + n16*520 + quad*8;
  i32x4 g[16];

  for (int t = 0; t < NSTEPS; ++t) {
    #pragma unroll
    for (int bi = 0; bi < 4; ++bi) {
      u32* r1g = ring1 + (size_t)bi * 65536;
      u32* r2g = ring2 + (size_t)bi * 65536;
      int* prg = prog + bi * 64;
      { const char* hp = (const char*)(r1g + (t&3)*16384) + arow*1024 + quad*32;
        TAGPOLL(h, hp, t+1); }        // h1_t (L0 leads; usually 1 poll)
      if (lane == 0)                  // read-progress for L0's anti-dep
        __hip_atomic_store(&prg[widx], t+1, __ATOMIC_RELAXED, __HIP_MEMORY_SCOPE_AGENT);
      f32x4 acc[4] = {{0,0,0,0},{0,0,0,0},{0,0,0,0},{0,0,0,0}};
      #pragma unroll
      for (int kc = 0; kc < 8; ++kc) {            // h1 half off the h2 cycle
        bf16x8 a = frag_from(h[2*kc], h[2*kc+1]);
        #pragma unroll
        for (int nt = 0; nt < 4; ++nt)
          acc[nt] = __builtin_amdgcn_mfma_f32_16x16x32_bf16(
              a, *(const bf16x8*)(bP + nt*16*520 + kc*32), acc[nt], 0,0,0);
      }
      { const char* hp = (const char*)(r2g + ((t+3)&3)*16384) + arow*1024 + quad*32;
        TAGPOLL(g, hp, t); }          // h2_{t-1}: tag t
      #pragma unroll
      for (int kc = 0; kc < 8; ++kc) {
        bf16x8 a = frag_from(g[2*kc], g[2*kc+1]);
        #pragma unroll
        for (int nt = 0; nt < 4; ++nt)
          acc[nt] = __builtin_amdgcn_mfma_f32_16x16x32_bf16(
              a, *(const bf16x8*)(bP + nt*16*520 + 256 + kc*32), acc[nt], 0,0,0);
      }
      u32 tag = ((u32)(t+1)) << 16;
      u32* dst = r2g + (t&3)*16384;
      #pragma unroll
      for (int r = 0; r < 4; ++r) {
        float gi = acc[0][r] + bg[0];
        float gf = acc[1][r] + bg[1];
        float gg = acc[2][r] + bg[2];
        float go = acc[3][r] + bg[3];
        float c  = sigf(gf)*cst[bi][r] + sigf(gi)*tanhf_(gg);
        cst[bi][r] = c;
        int rl = wv*16 + quad*4 + r;
        pub_u32(dst + rl*256 + j16 + n16, tag | (u32)f2bf(sigf(go)*tanhf_(c)));
      }
    }
  }

  // ============ epilogue: y = (h2_T @ W1^T + b1) @ W2^T + b2 ============
  // L1 block j handles batch rows j*16..j*16+15; h2_511 = tag 512, slot 3.
  {
    float* lastsh = (float*)smem;                 // 16 x 256 = 16 KB
    float* y1sh   = lastsh + 4096;                // 16 x 1280 = 80 KB
    float* psum   = y1sh + 20480;                 // 256
    __syncthreads();
    const u32* r2e = ring2 + (size_t)(j >> 2) * 65536 + 3*16384;
    {
      int row = tid >> 4, c16 = tid & 15;
      int lr = (j & 3)*16 + row;                  // group-local row
      #pragma unroll
      for (int k = 0; k < 8; ++k) {
        int cc = c16*8 + k;                       // u64 index: cols cc*2, cc*2+1
        const u64* p = (const u64*)((const char*)r2e + lr*1024 + cc*8);
        u64 v = 0; int it = 0;
        for (;;) {
          v = ld_u64_sc1(p);
          if (((v >> 16) & 0xffffull) == 512 && (v >> 48) == 512) break;
          if (++it > RETRY_LIM) break;
          __builtin_amdgcn_s_sleep(1);
        }
        lastsh[row*256 + cc*2 + 0] = bf2f((u16)(v & 0xffffu));
        lastsh[row*256 + cc*2 + 1] = bf2f((u16)((v >> 32) & 0xffffu));
      }
    }
    __syncthreads();
    for (int i = 0; i < 5; ++i) {
      int m = tid + i*256;
      const float4* wr4 = (const float4*)(W1 + (size_t)m*256);
      float a[16];
      #pragma unroll
      for (int jj = 0; jj < 16; ++jj) a[jj] = 0.f;
      for (int k4 = 0; k4 < 64; ++k4) {
        float4 w4 = wr4[k4];
        #pragma unroll
        for (int jj = 0; jj < 16; ++jj) {
          const float* ls = lastsh + jj*256 + k4*4;
          a[jj] += w4.x*ls[0] + w4.y*ls[1] + w4.z*ls[2] + w4.w*ls[3];
        }
      }
      float bb = b1[m];
      #pragma unroll
      for (int jj = 0; jj < 16; ++jj) y1sh[jj*1280 + m] = a[jj] + bb;
    }
    __syncthreads();
    {
      int row = tid >> 4, o = (tid >> 2) & 3, q = tid & 3;
      const float* w2r = W2 + (size_t)o*1280 + q*320;
      const float* yr  = y1sh + row*1280 + q*320;
      float s = 0.f;
      for (int m = 0; m < 320; ++m) s += w2r[m]*yr[m];
      psum[tid] = s;
    }
    __syncthreads();
    if (tid < 64) {
      int row = tid >> 2, o = tid & 3;
      out[(j*16 + row)*4 + o] = b2[o] + psum[row*16 + o*4 + 0]
                                      + psum[row*16 + o*4 + 1]
                                      + psum[row*16 + o*4 + 2]
                                      + psum[row*16 + o*4 + 3];
    }
  }
}

extern "C" void kernel_launch(void* const* d_in, const int* in_sizes, int n_in,
                              void* d_out, int out_size, void* d_ws, size_t ws_size,
                              hipStream_t stream) {
  (void)in_sizes; (void)n_in; (void)out_size; (void)ws_size;
  const float* x    = (const float*)d_in[0];
  const float* Wih0 = (const float*)d_in[1];
  const float* Whh0 = (const float*)d_in[2];
  const float* bih0 = (const float*)d_in[3];
  const float* bhh0 = (const float*)d_in[4];
  const float* Wih1 = (const float*)d_in[5];
  const float* Whh1 = (const float*)d_in[6];
  const float* bih1 = (const float*)d_in[7];
  const float* bhh1 = (const float*)d_in[8];
  const float* W1   = (const float*)d_in[9];
  const float* b1   = (const float*)d_in[10];
  const float* W2   = (const float*)d_in[11];
  const float* b2   = (const float*)d_in[12];
  float* out = (float*)d_out;
  char* ws   = (char*)d_ws;

  // zero rings (tag0 == h_{-1}=0) + prog flags; ws re-poisoned every call
  hipLaunchKernelGGL(ws_init_kernel, dim3((WS_TOTAL/4 + 255)/256), dim3(256),
                     0, stream, (int*)ws, (int)(WS_TOTAL/4));

  hipFuncSetAttribute((const void*)lstm_persistent,
                      hipFuncAttributeMaxDynamicSharedMemorySize, SMEM_BYTES);

  void* args[] = { (void*)&x, (void*)&Wih0, (void*)&Whh0, (void*)&bih0, (void*)&bhh0,
                   (void*)&Wih1, (void*)&Whh1, (void*)&bih1, (void*)&bhh1,
                   (void*)&W1, (void*)&b1, (void*)&W2, (void*)&b2,
                   (void*)&out, (void*)&ws };
  // cooperative launch: all 32 blocks co-resident (<= 256 CUs)
  hipLaunchCooperativeKernel((const void*)lstm_persistent, dim3(32), dim3(256),
                             args, SMEM_BYTES, stream);
}

// Round 8
// 3084.230 us; speedup vs baseline: 7.6147x; 2.9915x over previous
//
#include <hip/hip_runtime.h>
#include <stdint.h>

typedef unsigned short u16;
typedef unsigned int   u32;
typedef unsigned long long u64;
typedef __bf16 bf16_t;
typedef bf16_t bf16x8 __attribute__((ext_vector_type(8)));
typedef float  f32x4  __attribute__((ext_vector_type(4)));
typedef int    i32x4  __attribute__((ext_vector_type(4)));

#define NSTEPS 512
#define SPIN_LIM  (1<<17)
#define RETRY_LIM (1<<13)

// ---- workspace (bytes). Rings store u32 words: (step_tag<<16)|h_bf16 ->
// data is self-validating. Publish = relaxed agent-scope atomic swap
// (executes at LLC). R16 change vs R9 (2692us verified): TAGPOLL keeps
// the fast path (one full 16KB read, tag-verified) but on a stale first
// read it spins on a 64-line SAMPLE of the data (1 dword/lane at each
// producer-wave's last-published row) instead of re-reading the full
// tile -> kills the LLC poll storm (R9: 256 lines/wave/retry x 512
// waves) without adding any ordered hop (R11's flag mistake, 2.8x worse).
// LAUNCH ENVELOPE (measured this session): cooperative grid <= 128
// blocks AND dynamic LDS <= ~99KB; 256-block cooperative launches are
// rejected silently (R14/R15), LDS 133120 rejected (R10/R14).
// [R17 = R16 resubmitted verbatim: prior round was an infra failure
// ("container failed twice"), no signal obtained.]
#define WS_RING1 0u          /* [4 grp][4 slot][64 row][256 col] u32 h1 */
#define WS_RING2 1048576u    /* [4 grp][4 slot][64 row][256 col] u32 h2 */
#define WS_PROG  2097152u    /* [4 grp][64] int: L1 per-wave read progress */
#define WS_TOTAL 2098176u

#define SMEM_BYTES (64*520*2)   /* 66560: L1 weight slice (L0 uses 64*328*2) */

__device__ __forceinline__ u16 f2bf(float f) {
  u32 u = __float_as_uint(f);
  return (u16)((u + 0x7fffu + ((u >> 16) & 1u)) >> 16);   // RNE
}
__device__ __forceinline__ float bf2f(u16 b) { return __uint_as_float(((u32)b) << 16); }
__device__ __forceinline__ float sigf(float x) { return 1.f / (1.f + __expf(-x)); }
__device__ __forceinline__ float tanhf_(float x) {
  float e = __expf(-2.f * fabsf(x));
  float t = (1.f - e) / (1.f + e);
  return x >= 0.f ? t : -t;
}

// publish: atomic swap at agent scope -> RMW executed at the LLC,
// data visible at fabric latency, line resident for consumer polls.
__device__ __forceinline__ void pub_u32(u32* p, u32 v) {
  (void)__hip_atomic_exchange(p, v, __ATOMIC_RELAXED, __HIP_MEMORY_SCOPE_AGENT);
}
__device__ __forceinline__ u64 ld_u64_sc1(const u64* p) {
  u64 v; asm volatile("global_load_dwordx2 %0, %1, off sc1\n\ts_waitcnt vmcnt(0)"
                      : "=v"(v) : "v"(p) : "memory"); return v;
}
__device__ __forceinline__ u32 ld_u32_sc1(const u32* p) {
  u32 v; asm volatile("global_load_dword %0, %1, off sc1\n\ts_waitcnt vmcnt(0)"
                      : "=v"(v) : "v"(p) : "memory"); return v;
}

// 16 x 16B loads of a lane's 64 tagged words (8 chunks of 32 cols; lane
// covers cols quad*8..+7 of each chunk; row stride 1024B) + vmcnt(0).
#define LD16_W(A, P)                                                       \
  asm volatile(                                                            \
    "global_load_dwordx4 %0,  %16, off sc1\n\t"                            \
    "global_load_dwordx4 %1,  %16, off offset:16 sc1\n\t"                  \
    "global_load_dwordx4 %2,  %16, off offset:128 sc1\n\t"                 \
    "global_load_dwordx4 %3,  %16, off offset:144 sc1\n\t"                 \
    "global_load_dwordx4 %4,  %16, off offset:256 sc1\n\t"                 \
    "global_load_dwordx4 %5,  %16, off offset:272 sc1\n\t"                 \
    "global_load_dwordx4 %6,  %16, off offset:384 sc1\n\t"                 \
    "global_load_dwordx4 %7,  %16, off offset:400 sc1\n\t"                 \
    "global_load_dwordx4 %8,  %16, off offset:512 sc1\n\t"                 \
    "global_load_dwordx4 %9,  %16, off offset:528 sc1\n\t"                 \
    "global_load_dwordx4 %10, %16, off offset:640 sc1\n\t"                 \
    "global_load_dwordx4 %11, %16, off offset:656 sc1\n\t"                 \
    "global_load_dwordx4 %12, %16, off offset:768 sc1\n\t"                 \
    "global_load_dwordx4 %13, %16, off offset:784 sc1\n\t"                 \
    "global_load_dwordx4 %14, %16, off offset:896 sc1\n\t"                 \
    "global_load_dwordx4 %15, %16, off offset:912 sc1\n\t"                 \
    "s_waitcnt vmcnt(0)"                                                   \
    : "=&v"(A[0]), "=&v"(A[1]), "=&v"(A[2]),  "=&v"(A[3]),                 \
      "=&v"(A[4]), "=&v"(A[5]), "=&v"(A[6]),  "=&v"(A[7]),                 \
      "=&v"(A[8]), "=&v"(A[9]), "=&v"(A[10]), "=&v"(A[11]),                \
      "=&v"(A[12]),"=&v"(A[13]),"=&v"(A[14]), "=&v"(A[15])                 \
    : "v"(P) : "memory")

#define TAGCHK(A, TB, BAD) do {                                            \
    _Pragma("unroll")                                                      \
    for (int q_ = 0; q_ < 16; ++q_)                                        \
      BAD |= ((u32)A[q_][0] ^ TB) | ((u32)A[q_][1] ^ TB)                   \
           | ((u32)A[q_][2] ^ TB) | ((u32)A[q_][3] ^ TB);                  \
  } while (0)

// Sampled poll: fast path = one full tile read (tag-verified). If stale,
// spin on 1 dword/lane sampled at rows {15,31,47,63} x producer cols
// (each producer wave's last-published row) -- 64 cache lines/iter vs
// 256 -- then re-read the full tile. Tags on the full read remain the
// correctness guarantee; a passing sample with a straggling word just
// loops (rare, bounded by RETRY_LIM).
// SB = slot base (char*), LOFF = arow*1024+quad*32, SIDX = sample u32 idx.
#define TAGPOLL_S(A, SB, LOFF, SIDX, WANT) do {                            \
    u32 tb = ((u32)(WANT)) << 16;                                          \
    LD16_W(A, (const char*)(SB) + (LOFF));                                 \
    u32 bad = 0; TAGCHK(A, tb, bad); bad &= 0xffff0000u;                   \
    if (!__all(bad == 0)) {                                                \
      const u32* sp_ = (const u32*)(SB) + (SIDX);                          \
      int it_ = 0;                                                         \
      for (;;) {                                                           \
        u32 sv_ = ld_u32_sc1(sp_);                                         \
        if (__all((sv_ >> 16) == (u32)(WANT))) {                           \
          LD16_W(A, (const char*)(SB) + (LOFF));                           \
          bad = 0; TAGCHK(A, tb, bad); bad &= 0xffff0000u;                 \
          if (__all(bad == 0)) break;                                      \
        }                                                                  \
        if (++it_ > RETRY_LIM) break;                                      \
        __builtin_amdgcn_s_sleep(1);                                       \
      }                                                                    \
    }                                                                      \
  } while (0)

__device__ __forceinline__ bf16x8 frag_from(i32x4 lo, i32x4 hi) {
  union { u32 w[4]; bf16x8 v; } u_;
  u_.w[0] = ((u32)lo[0] & 0xffffu) | ((u32)lo[1] << 16);
  u_.w[1] = ((u32)lo[2] & 0xffffu) | ((u32)lo[3] << 16);
  u_.w[2] = ((u32)hi[0] & 0xffffu) | ((u32)hi[1] << 16);
  u_.w[3] = ((u32)hi[2] & 0xffffu) | ((u32)hi[3] << 16);
  return u_.v;
}
__device__ __forceinline__ bf16x8 pack_bf8(float4 a, float4 b) {
  union { u32 w[4]; bf16x8 v; } u_;
  u_.w[0] = (u32)f2bf(a.x) | ((u32)f2bf(a.y) << 16);
  u_.w[1] = (u32)f2bf(a.z) | ((u32)f2bf(a.w) << 16);
  u_.w[2] = (u32)f2bf(b.x) | ((u32)f2bf(b.y) << 16);
  u_.w[3] = (u32)f2bf(b.z) | ((u32)f2bf(b.w) << 16);
  return u_.v;
}

// anti-dep spin (L0, every 2nd step): lanes watch L1 read-progress words
__device__ __forceinline__ void spin64(const int* f, int lane, int target) {
  if (target <= 0) return;
  int it = 0;
  for (;;) {
    int v = __hip_atomic_load(&f[lane], __ATOMIC_RELAXED, __HIP_MEMORY_SCOPE_AGENT);
    if (__all(v >= target)) return;
    if (++it > SPIN_LIM) return;
    __builtin_amdgcn_s_sleep(2);
  }
}

__global__ void ws_init_kernel(int* p, int n) {
  int i = blockIdx.x * blockDim.x + threadIdx.x;
  if (i < n)    // agent-scope stores -> zeros at LLC (tag0 == h_{-1}=0)
    __hip_atomic_store(&p[i], 0, __ATOMIC_RELAXED, __HIP_MEMORY_SCOPE_AGENT);
}

// Pipelined persistent 2-layer LSTM, 128 blocks x 256 threads (R9
// structure, verified 2692us). blk<64: layer-0; blk>=64: layer-1 (+
// epilogue). b=blk&63: bi=b>>4 (batch group, 64 rows), j=b&15 (16-col
// slice). Wave wv = M-tile (16 rows). MFMA 16x16x32_bf16: A from tagged
// LLC ring (registers), B from row-major padded LDS, C/D col=lane&15,
// row=quad*4+reg -> acc[nt]=gate nt, lane-local pointwise, c-state in
// VGPRs. Sync: data-embedded step tags; publish via atomic swap;
// consumer polls = sampled-spin (R16).
__global__ void __launch_bounds__(256)
lstm_persistent(const float* __restrict__ x,
                const float* __restrict__ Wih0, const float* __restrict__ Whh0,
                const float* __restrict__ bih0, const float* __restrict__ bhh0,
                const float* __restrict__ Wih1, const float* __restrict__ Whh1,
                const float* __restrict__ bih1, const float* __restrict__ bhh1,
                const float* __restrict__ W1, const float* __restrict__ b1,
                const float* __restrict__ W2, const float* __restrict__ b2,
                float* __restrict__ out, char* __restrict__ ws)
{
  extern __shared__ u16 smem[];
  const int tid  = threadIdx.x;
  const int lane = tid & 63;
  const int wv   = tid >> 6;
  const int n16  = lane & 15;
  const int quad = lane >> 4;
  const int blk  = blockIdx.x;
  const int layer = blk >> 6;
  const int b    = blk & 63;
  const int bi   = b >> 4, j = b & 15;
  const int j16  = j * 16;
  const int rowg0 = bi * 64;
  const int widx = j*4 + wv;
  const int arow = wv*16 + n16;          // my A-row (group-local)
  const int loff = arow*1024 + quad*32;  // my full-read byte offset in slot
  const int sidx = (quad*16 + 15)*256 + n16*16 + 15;  // my sample word

  u32* r1g = (u32*)(ws + WS_RING1) + (size_t)bi * 4 * 16384;
  u32* r2g = (u32*)(ws + WS_RING2) + (size_t)bi * 4 * 16384;
  int* prg = (int*)(ws + WS_PROG) + bi * 64;

  float bg[4];
  #pragma unroll
  for (int nt = 0; nt < 4; ++nt) {
    int wrow = nt*256 + j16 + n16;
    bg[nt] = layer ? (bih1[wrow] + bhh1[wrow]) : (bih0[wrow] + bhh0[wrow]);
  }
  float cst[4] = {0.f,0.f,0.f,0.f};
  i32x4 h[16];

  if (layer == 0) {
    // ---- stage W0 slice fp32->bf16 into LDS, row-major stride 328 ----
    for (int i = 0; i < 20; ++i) {
      int u = tid + i*256;               // 64 rows x 80 float4
      int lr = u / 80, c4 = u % 80;
      int wrow = (lr >> 4)*256 + j16 + (lr & 15);
      float4 v = (c4 < 16) ? *(const float4*)(Wih0 + (size_t)wrow*64 + c4*4)
                           : *(const float4*)(Whh0 + (size_t)wrow*256 + (c4-16)*4);
      u16* d = smem + lr*328 + c4*4;
      d[0]=f2bf(v.x); d[1]=f2bf(v.y); d[2]=f2bf(v.z); d[3]=f2bf(v.w);
    }
    __syncthreads();
    const u16* bP = smem + n16*328 + quad*8;

    for (int t = 0; t < NSTEPS; ++t) {
      // x_t prefetch (in flight during spin/poll)
      const float* xp = x + ((size_t)(rowg0 + arow)*NSTEPS + t)*64 + quad*8;
      float4 xa = *(const float4*)(xp);
      float4 xb = *(const float4*)(xp + 4);
      float4 xc = *(const float4*)(xp + 32);
      float4 xd = *(const float4*)(xp + 36);
      if ((t & 1) == 0)
        spin64(prg, lane, t - 2);   // ring1 anti-dep, amortized over 2 steps
      TAGPOLL_S(h, (const char*)(r1g + ((t+3)&3)*16384), loff, sidx, t);
      bf16x8 a0 = pack_bf8(xa, xb), a1 = pack_bf8(xc, xd);
      f32x4 acc[4] = {{0,0,0,0},{0,0,0,0},{0,0,0,0},{0,0,0,0}};
      #pragma unroll
      for (int nt = 0; nt < 4; ++nt)
        acc[nt] = __builtin_amdgcn_mfma_f32_16x16x32_bf16(
            a0, *(const bf16x8*)(bP + nt*16*328), acc[nt], 0,0,0);
      #pragma unroll
      for (int nt = 0; nt < 4; ++nt)
        acc[nt] = __builtin_amdgcn_mfma_f32_16x16x32_bf16(
            a1, *(const bf16x8*)(bP + nt*16*328 + 32), acc[nt], 0,0,0);
      #pragma unroll
      for (int kc = 0; kc < 8; ++kc) {
        bf16x8 a = frag_from(h[2*kc], h[2*kc+1]);
        #pragma unroll
        for (int nt = 0; nt < 4; ++nt)
          acc[nt] = __builtin_amdgcn_mfma_f32_16x16x32_bf16(
              a, *(const bf16x8*)(bP + nt*16*328 + 64 + kc*32), acc[nt], 0,0,0);
      }
      u32 tag = ((u32)(t+1)) << 16;
      u32* dst = r1g + (t&3)*16384;
      #pragma unroll
      for (int r = 0; r < 4; ++r) {
        float gi = acc[0][r] + bg[0];
        float gf = acc[1][r] + bg[1];
        float gg = acc[2][r] + bg[2];
        float go = acc[3][r] + bg[3];
        float c  = sigf(gf)*cst[r] + sigf(gi)*tanhf_(gg);
        cst[r] = c;
        int rl = wv*16 + quad*4 + r;
        pub_u32(dst + rl*256 + j16 + n16, tag | (u32)f2bf(sigf(go)*tanhf_(c)));
      }
      // no drain, no flag: consumers poll the tagged data itself
    }
    return;
  }

  // ======================= LAYER-1 WORKER =======================
  for (int i = 0; i < 32; ++i) {
    int u = tid + i*256;               // 64 rows x 128 float4 ([Wih1|Whh1])
    int lr = u >> 7, c4 = u & 127;
    int wrow = (lr >> 4)*256 + j16 + (lr & 15);
    float4 v = (c4 < 64) ? *(const float4*)(Wih1 + (size_t)wrow*256 + c4*4)
                         : *(const float4*)(Whh1 + (size_t)wrow*256 + (c4-64)*4);
    u16* d = smem + lr*520 + c4*4;
    d[0]=f2bf(v.x); d[1]=f2bf(v.y); d[2]=f2bf(v.z); d[3]=f2bf(v.w);
  }
  __syncthreads();
  const u16* bP = smem + n16*520 + quad*8;
  i32x4 g[16];

  for (int t = 0; t < NSTEPS; ++t) {
    TAGPOLL_S(h, (const char*)(r1g + (t&3)*16384), loff, sidx, t+1);  // h1_t
    if (lane == 0)                  // read-progress for L0's anti-dep
      __hip_atomic_store(&prg[widx], t+1, __ATOMIC_RELAXED, __HIP_MEMORY_SCOPE_AGENT);
    f32x4 acc[4] = {{0,0,0,0},{0,0,0,0},{0,0,0,0},{0,0,0,0}};
    #pragma unroll
    for (int kc = 0; kc < 8; ++kc) {            // h1 half off the h2 cycle
      bf16x8 a = frag_from(h[2*kc], h[2*kc+1]);
      #pragma unroll
      for (int nt = 0; nt < 4; ++nt)
        acc[nt] = __builtin_amdgcn_mfma_f32_16x16x32_bf16(
            a, *(const bf16x8*)(bP + nt*16*520 + kc*32), acc[nt], 0,0,0);
    }
    TAGPOLL_S(g, (const char*)(r2g + ((t+3)&3)*16384), loff, sidx, t);  // h2_{t-1}
    #pragma unroll
    for (int kc = 0; kc < 8; ++kc) {
      bf16x8 a = frag_from(g[2*kc], g[2*kc+1]);
      #pragma unroll
      for (int nt = 0; nt < 4; ++nt)
        acc[nt] = __builtin_amdgcn_mfma_f32_16x16x32_bf16(
            a, *(const bf16x8*)(bP + nt*16*520 + 256 + kc*32), acc[nt], 0,0,0);
    }
    u32 tag = ((u32)(t+1)) << 16;
    u32* dst = r2g + (t&3)*16384;
    #pragma unroll
    for (int r = 0; r < 4; ++r) {
      float gi = acc[0][r] + bg[0];
      float gf = acc[1][r] + bg[1];
      float gg = acc[2][r] + bg[2];
      float go = acc[3][r] + bg[3];
      float c  = sigf(gf)*cst[r] + sigf(gi)*tanhf_(gg);
      cst[r] = c;
      int rl = wv*16 + quad*4 + r;
      pub_u32(dst + rl*256 + j16 + n16, tag | (u32)f2bf(sigf(go)*tanhf_(c)));
    }
  }

  // ============ epilogue: y = (h2_T @ W1^T + b1) @ W2^T + b2 ============
  // L1 block b handles batch rows b*4..b*4+3; h2_511 = tag 512 in slot 3.
  {
    float* lastsh = (float*)smem;                 // 4x256
    float* y1sh   = lastsh + 1024;                // 4x1280
    float* psum   = y1sh + 5120;                  // 64
    __syncthreads();
    {
      int row = tid >> 6, c = tid & 63;
      int lr = (b & 15)*4 + row;                  // group-local row
      #pragma unroll
      for (int rep = 0; rep < 2; ++rep) {
        int cc = c + rep*64;                      // u64 index: cols cc*2, cc*2+1
        const u64* p = (const u64*)((const char*)(r2g + 3*16384) + lr*1024 + cc*8);
        u64 v = 0; int it = 0;
        for (;;) {
          v = ld_u64_sc1(p);
          if (((v >> 16) & 0xffffull) == 512 && (v >> 48) == 512) break;
          if (++it > RETRY_LIM) break;
          __builtin_amdgcn_s_sleep(1);
        }
        lastsh[row*256 + cc*2 + 0] = bf2f((u16)(v & 0xffffu));
        lastsh[row*256 + cc*2 + 1] = bf2f((u16)((v >> 32) & 0xffffu));
      }
    }
    __syncthreads();
    for (int i = 0; i < 5; ++i) {
      int m = tid + i*256;
      const float* wr = W1 + (size_t)m*256;
      float a0=0.f,a1=0.f,a2=0.f,a3=0.f;
      for (int k = 0; k < 256; ++k) {
        float w = wr[k];
        a0 += w*lastsh[k];     a1 += w*lastsh[256+k];
        a2 += w*lastsh[512+k]; a3 += w*lastsh[768+k];
      }
      float bb = b1[m];
      y1sh[m] = a0+bb; y1sh[1280+m] = a1+bb; y1sh[2560+m] = a2+bb; y1sh[3840+m] = a3+bb;
    }
    __syncthreads();
    if (tid < 64) {
      int row = tid >> 4, o = (tid >> 2) & 3, q = tid & 3;
      const float* w2r = W2 + (size_t)o*1280 + q*320;
      const float* yr  = y1sh + row*1280 + q*320;
      float s = 0.f;
      for (int m = 0; m < 320; ++m) s += w2r[m]*yr[m];
      psum[tid] = s;
    }
    __syncthreads();
    if (tid < 16) {
      int row = tid >> 2, o = tid & 3;
      out[(b*4 + row)*4 + o] = b2[o] + psum[tid*4+0] + psum[tid*4+1]
                                     + psum[tid*4+2] + psum[tid*4+3];
    }
  }
}

extern "C" void kernel_launch(void* const* d_in, const int* in_sizes, int n_in,
                              void* d_out, int out_size, void* d_ws, size_t ws_size,
                              hipStream_t stream) {
  (void)in_sizes; (void)n_in; (void)out_size; (void)ws_size;
  const float* x    = (const float*)d_in[0];
  const float* Wih0 = (const float*)d_in[1];
  const float* Whh0 = (const float*)d_in[2];
  const float* bih0 = (const float*)d_in[3];
  const float* bhh0 = (const float*)d_in[4];
  const float* Wih1 = (const float*)d_in[5];
  const float* Whh1 = (const float*)d_in[6];
  const float* bih1 = (const float*)d_in[7];
  const float* bhh1 = (const float*)d_in[8];
  const float* W1   = (const float*)d_in[9];
  const float* b1   = (const float*)d_in[10];
  const float* W2   = (const float*)d_in[11];
  const float* b2   = (const float*)d_in[12];
  float* out = (float*)d_out;
  char* ws   = (char*)d_ws;

  // zero rings (tag0 == h_{-1}=0) + prog flags; ws re-poisoned every call
  hipLaunchKernelGGL(ws_init_kernel, dim3((WS_TOTAL/4 + 255)/256), dim3(256),
                     0, stream, (int*)ws, (int)(WS_TOTAL/4));

  hipFuncSetAttribute((const void*)lstm_persistent,
                      hipFuncAttributeMaxDynamicSharedMemorySize, SMEM_BYTES);

  void* args[] = { (void*)&x, (void*)&Wih0, (void*)&Whh0, (void*)&bih0, (void*)&bhh0,
                   (void*)&Wih1, (void*)&Whh1, (void*)&bih1, (void*)&bhh1,
                   (void*)&W1, (void*)&b1, (void*)&W2, (void*)&b2,
                   (void*)&out, (void*)&ws };
  // cooperative launch: 128 blocks x 256 threads, 66560 LDS -- the
  // PROVEN launch envelope (<=128 blocks, <=99KB dyn-LDS).
  hipLaunchCooperativeKernel((const void*)lstm_persistent, dim3(128), dim3(256),
                             args, SMEM_BYTES, stream);
}